// Round 2
// baseline (250.906 us; speedup 1.0000x reference)
//
#include <hip/hip_runtime.h>

// Idealizer: torsion angles + backbone frames -> atom14 coordinates.
// One thread per residue, grid-stride. Tables staged in LDS once per block.
// Group-scatter placement: walk groups 0..7 (kinematic chain), cndmask-select
// the matching group's placement per atom (exactly one matches), apply the
// 0/1 atom mask as a final select via a packed bitmap.
//
// R1 post-mortem: 176 VGPRs -> ~10% occupancy, VALUBusy 31%, latency-bound.
// R2: VGPR diet (packed group nibbles + mask bitmap, no per-atom mask regs),
// __launch_bounds__(256,4), 1024 persistent blocks.

struct F3 { float x, y, z; };

__device__ __forceinline__ F3 f3sub(F3 a, F3 b) { return {a.x-b.x, a.y-b.y, a.z-b.z}; }
__device__ __forceinline__ F3 f3cross(F3 a, F3 b) {
    return {a.y*b.z - a.z*b.y, a.z*b.x - a.x*b.z, a.x*b.y - a.y*b.x};
}
__device__ __forceinline__ float f3dot(F3 a, F3 b) { return a.x*b.x + a.y*b.y + a.z*b.z; }

// sin/cos of the dihedral angle directly (reference takes sincos(atan2(y,x))).
__device__ __forceinline__ void dihedral_sc(F3 p0, F3 p1, F3 p2, F3 p3,
                                            float& s, float& c) {
    F3 b0 = f3sub(p0, p1);          // -(p1 - p0)
    F3 b1 = f3sub(p2, p1);
    F3 b2 = f3sub(p3, p2);
    F3 u = f3cross(b0, b1);
    F3 v = f3cross(b2, b1);         // ref's "b1xb2" is cross(b2, b1)
    F3 w = f3cross(u, v);
    float y = f3dot(w, b1) * rsqrtf(fmaxf(f3dot(b1, b1), 1e-30f));
    float x = f3dot(u, v);
    float r2 = x*x + y*y;
    if (r2 > 1e-24f) {
        float rinv = rsqrtf(r2);
        s = y * rinv;
        c = x * rinv;
    } else {                        // atan2(0,0)=0 -> angle 0
        s = 0.0f;
        c = 1.0f;
    }
}

#define DF_STRIDE 132   // 128 + 4 pad dwords: spread per-aa rows across banks
#define LIT_STRIDE 36   // 30 used + 6 pad: 16B-aligned rows, bank spread

__global__ __launch_bounds__(256, 4) void idealizer_kernel(
    const int*   __restrict__ aa,       // (n,)
    const float* __restrict__ bb,       // (n,4,3)
    const float* __restrict__ tor,      // (n,4)
    const float* __restrict__ dframes,  // (21,8,4,4)
    const int*   __restrict__ gidx,     // (21,14)
    const float* __restrict__ amask,    // (21,14)
    const float* __restrict__ lit,      // (21,14,3)
    float*       __restrict__ out,      // (n,14,3)
    int n)
{
    __shared__ __align__(16) float s_df[21 * DF_STRIDE];
    __shared__ __align__(16) float s_lit[21 * LIT_STRIDE];   // atoms 4..13 only
    __shared__ unsigned s_gpk[21];   // 10 x 3-bit group ids (atoms 4..13)
    __shared__ unsigned s_mbit[21];  // 10 x 1-bit atom mask (atoms 4..13)

    const int tid = threadIdx.x;
    for (int j = tid; j < 21 * 128; j += 256)
        s_df[(j >> 7) * DF_STRIDE + (j & 127)] = dframes[j];
    for (int j = tid; j < 21 * 30; j += 256) {
        int a = j / 30, r = j - a * 30;
        s_lit[a * LIT_STRIDE + r] = lit[a * 42 + 12 + r];
    }
    if (tid < 21) {
        unsigned gp = 0, mb = 0;
        #pragma unroll
        for (int a = 0; a < 10; a++) {
            gp |= ((unsigned)gidx[tid * 14 + 4 + a]) << (3 * a);
            mb |= (amask[tid * 14 + 4 + a] != 0.0f ? 1u : 0u) << a;
        }
        s_gpk[tid] = gp;
        s_mbit[tid] = mb;
    }
    __syncthreads();

    for (int i = blockIdx.x * 256 + tid; i < n; i += gridDim.x * 256) {
        // ---- own residue backbone (12 floats) ----
        const float4* bb4 = (const float4*)bb;
        float4 q0 = bb4[i * 3 + 0];   // N.xyz, CA.x
        float4 q1 = bb4[i * 3 + 1];   // CA.yz, C.xy
        float4 q2 = bb4[i * 3 + 2];   // C.z, atom3.xyz
        F3 Np  = {q0.x, q0.y, q0.z};
        F3 CAp = {q0.w, q1.x, q1.y};
        F3 Cp  = {q1.z, q1.w, q2.x};

        // ---- neighbors (clamped; boundary angles overridden below) ----
        const int im = (i > 0)     ? i - 1 : 0;
        const int ip = (i < n - 1) ? i + 1 : 0;
        F3 Cm = { bb[im * 12 + 6], bb[im * 12 + 7], bb[im * 12 + 8] };   // C[i-1]
        float4 r0 = bb4[ip * 3 + 0];                                      // N[i+1], CA[i+1].x
        float2 r1 = ((const float2*)bb)[ip * 6 + 2];                      // CA[i+1].yz
        F3 Nn  = {r0.x, r0.y, r0.z};
        F3 CAn = {r0.w, r1.x, r1.y};

        // ---- write backbone passthrough early (atoms 0..3) ----
        float2* o2 = (float2*)(out + (size_t)i * 42);
        o2[0] = make_float2(q0.x, q0.y);
        o2[1] = make_float2(q0.z, q0.w);
        o2[2] = make_float2(q1.x, q1.y);
        o2[3] = make_float2(q1.z, q1.w);
        o2[4] = make_float2(q2.x, q2.y);
        o2[5] = make_float2(q2.z, q2.w);

        // ---- backbone dihedrals (sin/cos directly) ----
        float s_ph, c_ph, s_ps, c_ps, s_om, c_om;
        dihedral_sc(Cm,  Np,  CAp, Cp,  s_ph, c_ph);   // phi
        dihedral_sc(Np,  CAp, Cp,  Nn,  s_ps, c_ps);   // psi
        dihedral_sc(CAp, Cp,  Nn,  CAn, s_om, c_om);   // omega
        if (i == 0)     { s_ph = 0.0f; c_ph = 1.0f; }
        if (i == n - 1) { s_ps = 0.0f; c_ps = 1.0f; s_om = 0.0f; c_om = 1.0f; }

        // ---- backbone frame from reference (N, CA, C) ----
        const float eps = 1e-20f;
        F3 nv = f3sub(Np, CAp);
        F3 cv = f3sub(Cp, CAp);
        float cx = cv.x, cy = cv.y, cz = cv.z;
        float d2xy  = cx * cx + cy * cy;
        float inrm  = rsqrtf(eps + d2xy);
        float s1 = -cy * inrm, c1 = cx * inrm;
        float inrm2 = rsqrtf(eps + d2xy + cz * cz);
        float s2 = cz * inrm2, c2 = sqrtf(d2xy) * inrm2;
        float Rc00 = c2 * c1,  Rc01 = -c2 * s1, Rc02 = s2;
        float Rc10 = s1,       Rc11 = c1,       Rc12 = 0.0f;
        float Rc20 = -s2 * c1, Rc21 = s2 * s1,  Rc22 = c2;
        float n2y = Rc10 * nv.x + Rc11 * nv.y + Rc12 * nv.z;
        float n2z = Rc20 * nv.x + Rc21 * nv.y + Rc22 * nv.z;
        float inrm3 = rsqrtf(eps + n2y * n2y + n2z * n2z);
        float sn = -n2z * inrm3, cn = n2y * inrm3;
        float M10 = cn * Rc10 - sn * Rc20, M11 = cn * Rc11 - sn * Rc21, M12 = cn * Rc12 - sn * Rc22;
        float M20 = sn * Rc10 + cn * Rc20, M21 = sn * Rc11 + cn * Rc21, M22 = sn * Rc12 + cn * Rc22;
        // bb_r = (Rn @ Rc)^T
        float B00 = Rc00, B01 = M10, B02 = M20;
        float B10 = Rc01, B11 = M11, B12 = M21;
        float B20 = Rc02, B21 = M12, B22 = M22;

        // ---- per-frame sin/cos: [identity, omega, phi, psi, tor0..3] ----
        float4 tv = ((const float4*)tor)[i];
        float sang[8], cang[8];
        sang[0] = 0.0f; cang[0] = 1.0f;
        sang[1] = s_om; cang[1] = c_om;
        sang[2] = s_ph; cang[2] = c_ph;
        sang[3] = s_ps; cang[3] = c_ps;
        __sincosf(tv.x, &sang[4], &cang[4]);
        __sincosf(tv.y, &sang[5], &cang[5]);
        __sincosf(tv.z, &sang[6], &cang[6]);
        __sincosf(tv.w, &sang[7], &cang[7]);

        // ---- hoist per-atom tables (packed + lit positions) ----
        const int aai = aa[i];
        const unsigned gpk  = s_gpk[aai];
        const unsigned mbit = s_mbit[aai];
        float la[30];
        {
            const float4* lr4 = (const float4*)&s_lit[aai * LIT_STRIDE];
            #pragma unroll
            for (int k = 0; k < 7; k++) {
                float4 t = lr4[k];
                la[4*k] = t.x; la[4*k+1] = t.y; la[4*k+2] = t.z; la[4*k+3] = t.w;
            }
            float2 t2 = ((const float2*)&s_lit[aai * LIT_STRIDE])[14];
            la[28] = t2.x; la[29] = t2.y;
        }

        float axv[10], ayv[10], azv[10];
        #pragma unroll
        for (int a = 0; a < 10; a++) { axv[a] = 0.0f; ayv[a] = 0.0f; azv[a] = 0.0f; }

        // ---- group chain ----
        float G00, G01, G02, G10, G11, G12, G20, G21, G22, Gx, Gy, Gz;
        const int dbase = aai * DF_STRIDE;
        #pragma unroll
        for (int g = 0; g < 8; g++) {
            const float4* dfr = (const float4*)&s_df[dbase + g * 16];
            float4 d0 = dfr[0], d1 = dfr[1], d2 = dfr[2];
            float sA = sang[g], cA = cang[g];
            // fr = dr @ Ra(angle)
            float f00 = d0.x, f01 = cA * d0.y + sA * d0.z, f02 = cA * d0.z - sA * d0.y;
            float f10 = d1.x, f11 = cA * d1.y + sA * d1.z, f12 = cA * d1.z - sA * d1.y;
            float f20 = d2.x, f21 = cA * d2.y + sA * d2.z, f22 = cA * d2.z - sA * d2.y;
            float A00, A01, A02, A10, A11, A12, A20, A21, A22, Atx, Aty, Atz;
            if (g <= 4) {
                A00 = B00; A01 = B01; A02 = B02;
                A10 = B10; A11 = B11; A12 = B12;
                A20 = B20; A21 = B21; A22 = B22;
                Atx = CAp.x; Aty = CAp.y; Atz = CAp.z;
            } else {
                A00 = G00; A01 = G01; A02 = G02;
                A10 = G10; A11 = G11; A12 = G12;
                A20 = G20; A21 = G21; A22 = G22;
                Atx = Gx; Aty = Gy; Atz = Gz;
            }
            float n00 = A00 * f00 + A01 * f10 + A02 * f20;
            float n01 = A00 * f01 + A01 * f11 + A02 * f21;
            float n02 = A00 * f02 + A01 * f12 + A02 * f22;
            float n10 = A10 * f00 + A11 * f10 + A12 * f20;
            float n11 = A10 * f01 + A11 * f11 + A12 * f21;
            float n12 = A10 * f02 + A11 * f12 + A12 * f22;
            float n20 = A20 * f00 + A21 * f10 + A22 * f20;
            float n21 = A20 * f01 + A21 * f11 + A22 * f21;
            float n22 = A20 * f02 + A21 * f12 + A22 * f22;
            float ntx = A00 * d0.w + A01 * d1.w + A02 * d2.w + Atx;
            float nty = A10 * d0.w + A11 * d1.w + A12 * d2.w + Aty;
            float ntz = A20 * d0.w + A21 * d1.w + A22 * d2.w + Atz;
            G00 = n00; G01 = n01; G02 = n02;
            G10 = n10; G11 = n11; G12 = n12;
            G20 = n20; G21 = n21; G22 = n22;
            Gx = ntx; Gy = nty; Gz = ntz;

            // select placement for atoms whose group == g (exactly one match)
            #pragma unroll
            for (int a = 0; a < 10; a++) {
                bool sel = ((gpk >> (3 * a)) & 7u) == (unsigned)g;
                float px = fmaf(G00, la[3*a], fmaf(G01, la[3*a+1], fmaf(G02, la[3*a+2], Gx)));
                float py = fmaf(G10, la[3*a], fmaf(G11, la[3*a+1], fmaf(G12, la[3*a+2], Gy)));
                float pz = fmaf(G20, la[3*a], fmaf(G21, la[3*a+1], fmaf(G22, la[3*a+2], Gz)));
                axv[a] = sel ? px : axv[a];
                ayv[a] = sel ? py : ayv[a];
                azv[a] = sel ? pz : azv[a];
            }
        }

        // ---- apply 0/1 atom mask as select, store atoms 4..13 ----
        float v[30];
        #pragma unroll
        for (int a = 0; a < 10; a++) {
            bool m = (mbit >> a) & 1u;
            v[3*a]   = m ? axv[a] : 0.0f;
            v[3*a+1] = m ? ayv[a] : 0.0f;
            v[3*a+2] = m ? azv[a] : 0.0f;
        }
        #pragma unroll
        for (int k = 0; k < 15; k++)
            o2[6 + k] = make_float2(v[2*k], v[2*k+1]);
    }
}

extern "C" void kernel_launch(void* const* d_in, const int* in_sizes, int n_in,
                              void* d_out, int out_size, void* d_ws, size_t ws_size,
                              hipStream_t stream) {
    const int*   aa  = (const int*)d_in[0];
    const float* bb  = (const float*)d_in[1];
    const float* tor = (const float*)d_in[2];
    const float* df  = (const float*)d_in[3];
    const int*   gi  = (const int*)d_in[4];
    const float* am  = (const float*)d_in[5];
    const float* lp  = (const float*)d_in[6];
    float* outp = (float*)d_out;
    const int n = in_sizes[0];
    int tiles = (n + 255) / 256;
    int blocks = tiles < 1024 ? tiles : 1024;   // persistent-ish grid-stride
    idealizer_kernel<<<blocks, 256, 0, stream>>>(aa, bb, tor, df, gi, am, lp, outp, n);
}

// Round 4
// 185.376 us; speedup vs baseline: 1.3535x; 1.3535x over previous
//
#include <hip/hip_runtime.h>

// Idealizer: torsion angles + backbone frames -> atom14 coordinates.
// One thread per residue, grid-stride (1024 blocks ~= fully persistent).
// Tables staged in LDS once per block. Group-scatter placement: walk groups
// 0..7 (kinematic chain); each atom is stored DIRECTLY at its (unique)
// matching group -- no accumulator array, lit positions read from LDS only
// inside the selected branch (keeps live VGPRs ~<=128).
//
// R1: 176 VGPR -> 2 waves/SIMD, VALUBusy 31%, latency-bound, 93 us.
// R2: __launch_bounds__(256,4) forced 64 VGPR -> scratch spill (WRITE 415 MB),
//     159 us. Lesson: never cap below the live set.
// R3: direct predicated stores; bench aborted with no counters (suspected
//     infra flake -- kernel audited in-bounds). R4 retries the structure
//     with the la[30] hoist removed (-30 live regs).

struct F3 { float x, y, z; };

__device__ __forceinline__ F3 f3sub(F3 a, F3 b) { return {a.x-b.x, a.y-b.y, a.z-b.z}; }
__device__ __forceinline__ F3 f3cross(F3 a, F3 b) {
    return {a.y*b.z - a.z*b.y, a.z*b.x - a.x*b.z, a.x*b.y - a.y*b.x};
}
__device__ __forceinline__ float f3dot(F3 a, F3 b) { return a.x*b.x + a.y*b.y + a.z*b.z; }

// sin/cos of the dihedral angle directly (reference takes sincos(atan2(y,x))).
__device__ __forceinline__ void dihedral_sc(F3 p0, F3 p1, F3 p2, F3 p3,
                                            float& s, float& c) {
    F3 b0 = f3sub(p0, p1);          // -(p1 - p0)
    F3 b1 = f3sub(p2, p1);
    F3 b2 = f3sub(p3, p2);
    F3 u = f3cross(b0, b1);
    F3 v = f3cross(b2, b1);         // ref's "b1xb2" is cross(b2, b1)
    F3 w = f3cross(u, v);
    float y = f3dot(w, b1) * rsqrtf(fmaxf(f3dot(b1, b1), 1e-30f));
    float x = f3dot(u, v);
    float r2 = x*x + y*y;
    if (r2 > 1e-24f) {
        float rinv = rsqrtf(r2);
        s = y * rinv;
        c = x * rinv;
    } else {                        // atan2(0,0)=0 -> angle 0
        s = 0.0f;
        c = 1.0f;
    }
}

#define DF_STRIDE 132   // 128 + 4 pad dwords: spread per-aa rows across banks
#define LIT_STRIDE 36   // 30 used + 6 pad: 16B-aligned rows, bank spread

__global__ __launch_bounds__(256) void idealizer_kernel(
    const int*   __restrict__ aa,       // (n,)
    const float* __restrict__ bb,       // (n,4,3)
    const float* __restrict__ tor,      // (n,4)
    const float* __restrict__ dframes,  // (21,8,4,4)
    const int*   __restrict__ gidx,     // (21,14)
    const float* __restrict__ amask,    // (21,14)
    const float* __restrict__ lit,      // (21,14,3)
    float*       __restrict__ out,      // (n,14,3)
    int n)
{
    __shared__ __align__(16) float s_df[21 * DF_STRIDE];
    __shared__ __align__(16) float s_lit[21 * LIT_STRIDE];   // atoms 4..13 only
    __shared__ unsigned s_gpk[21];   // 10 x 3-bit group ids (atoms 4..13)
    __shared__ unsigned s_mbit[21];  // 10 x 1-bit atom mask (atoms 4..13)

    const int tid = threadIdx.x;
    for (int j = tid; j < 21 * 128; j += 256)
        s_df[(j >> 7) * DF_STRIDE + (j & 127)] = dframes[j];
    for (int j = tid; j < 21 * 30; j += 256) {
        int a = j / 30, r = j - a * 30;
        s_lit[a * LIT_STRIDE + r] = lit[a * 42 + 12 + r];
    }
    if (tid < 21) {
        unsigned gp = 0, mb = 0;
        #pragma unroll
        for (int a = 0; a < 10; a++) {
            gp |= ((unsigned)gidx[tid * 14 + 4 + a]) << (3 * a);
            mb |= (amask[tid * 14 + 4 + a] != 0.0f ? 1u : 0u) << a;
        }
        s_gpk[tid] = gp;
        s_mbit[tid] = mb;
    }
    __syncthreads();

    for (int i = blockIdx.x * 256 + tid; i < n; i += gridDim.x * 256) {
        // ---- own residue backbone (12 floats) ----
        const float4* bb4 = (const float4*)bb;
        float4 q0 = bb4[i * 3 + 0];   // N.xyz, CA.x
        float4 q1 = bb4[i * 3 + 1];   // CA.yz, C.xy
        float4 q2 = bb4[i * 3 + 2];   // C.z, atom3.xyz
        F3 Np  = {q0.x, q0.y, q0.z};
        F3 CAp = {q0.w, q1.x, q1.y};
        F3 Cp  = {q1.z, q1.w, q2.x};

        // ---- neighbors (clamped; boundary angles overridden below) ----
        const int im = (i > 0)     ? i - 1 : 0;
        const int ip = (i < n - 1) ? i + 1 : 0;
        F3 Cm = { bb[im * 12 + 6], bb[im * 12 + 7], bb[im * 12 + 8] };   // C[i-1]
        float4 r0 = bb4[ip * 3 + 0];                                      // N[i+1], CA[i+1].x
        float2 r1 = ((const float2*)bb)[ip * 6 + 2];                      // CA[i+1].yz
        F3 Nn  = {r0.x, r0.y, r0.z};
        F3 CAn = {r0.w, r1.x, r1.y};

        // ---- write backbone passthrough early (atoms 0..3) ----
        float* orow = out + (size_t)i * 42;
        float2* o2 = (float2*)orow;
        o2[0] = make_float2(q0.x, q0.y);
        o2[1] = make_float2(q0.z, q0.w);
        o2[2] = make_float2(q1.x, q1.y);
        o2[3] = make_float2(q1.z, q1.w);
        o2[4] = make_float2(q2.x, q2.y);
        o2[5] = make_float2(q2.z, q2.w);

        // ---- backbone dihedrals (sin/cos directly) ----
        float s_ph, c_ph, s_ps, c_ps, s_om, c_om;
        dihedral_sc(Cm,  Np,  CAp, Cp,  s_ph, c_ph);   // phi
        dihedral_sc(Np,  CAp, Cp,  Nn,  s_ps, c_ps);   // psi
        dihedral_sc(CAp, Cp,  Nn,  CAn, s_om, c_om);   // omega
        if (i == 0)     { s_ph = 0.0f; c_ph = 1.0f; }
        if (i == n - 1) { s_ps = 0.0f; c_ps = 1.0f; s_om = 0.0f; c_om = 1.0f; }

        // ---- backbone frame from reference (N, CA, C) ----
        const float eps = 1e-20f;
        F3 nv = f3sub(Np, CAp);
        F3 cv = f3sub(Cp, CAp);
        float cx = cv.x, cy = cv.y, cz = cv.z;
        float d2xy  = cx * cx + cy * cy;
        float inrm  = rsqrtf(eps + d2xy);
        float s1 = -cy * inrm, c1 = cx * inrm;
        float inrm2 = rsqrtf(eps + d2xy + cz * cz);
        float s2 = cz * inrm2, c2 = sqrtf(d2xy) * inrm2;
        float Rc00 = c2 * c1,  Rc01 = -c2 * s1, Rc02 = s2;
        float Rc10 = s1,       Rc11 = c1,       Rc12 = 0.0f;
        float Rc20 = -s2 * c1, Rc21 = s2 * s1,  Rc22 = c2;
        float n2y = Rc10 * nv.x + Rc11 * nv.y + Rc12 * nv.z;
        float n2z = Rc20 * nv.x + Rc21 * nv.y + Rc22 * nv.z;
        float inrm3 = rsqrtf(eps + n2y * n2y + n2z * n2z);
        float sn = -n2z * inrm3, cn = n2y * inrm3;
        float M10 = cn * Rc10 - sn * Rc20, M11 = cn * Rc11 - sn * Rc21, M12 = cn * Rc12 - sn * Rc22;
        float M20 = sn * Rc10 + cn * Rc20, M21 = sn * Rc11 + cn * Rc21, M22 = sn * Rc12 + cn * Rc22;
        // bb_r = (Rn @ Rc)^T
        float B00 = Rc00, B01 = M10, B02 = M20;
        float B10 = Rc01, B11 = M11, B12 = M21;
        float B20 = Rc02, B21 = M12, B22 = M22;

        // ---- per-frame sin/cos: [identity, omega, phi, psi, tor0..3] ----
        float4 tv = ((const float4*)tor)[i];
        float sang[8], cang[8];
        sang[0] = 0.0f; cang[0] = 1.0f;
        sang[1] = s_om; cang[1] = c_om;
        sang[2] = s_ph; cang[2] = c_ph;
        sang[3] = s_ps; cang[3] = c_ps;
        __sincosf(tv.x, &sang[4], &cang[4]);
        __sincosf(tv.y, &sang[5], &cang[5]);
        __sincosf(tv.z, &sang[6], &cang[6]);
        __sincosf(tv.w, &sang[7], &cang[7]);

        const int aai = aa[i];
        const unsigned gpk  = s_gpk[aai];
        const unsigned mbit = s_mbit[aai];
        const float* lrow = &s_lit[aai * LIT_STRIDE];

        // ---- group chain; store each atom at its (unique) matching group ----
        float G00, G01, G02, G10, G11, G12, G20, G21, G22, Gx, Gy, Gz;
        const int dbase = aai * DF_STRIDE;
        #pragma unroll
        for (int g = 0; g < 8; g++) {
            const float4* dfr = (const float4*)&s_df[dbase + g * 16];
            float4 d0 = dfr[0], d1 = dfr[1], d2 = dfr[2];
            float sA = sang[g], cA = cang[g];
            // fr = dr @ Ra(angle)
            float f00 = d0.x, f01 = cA * d0.y + sA * d0.z, f02 = cA * d0.z - sA * d0.y;
            float f10 = d1.x, f11 = cA * d1.y + sA * d1.z, f12 = cA * d1.z - sA * d1.y;
            float f20 = d2.x, f21 = cA * d2.y + sA * d2.z, f22 = cA * d2.z - sA * d2.y;
            float A00, A01, A02, A10, A11, A12, A20, A21, A22, Atx, Aty, Atz;
            if (g <= 4) {
                A00 = B00; A01 = B01; A02 = B02;
                A10 = B10; A11 = B11; A12 = B12;
                A20 = B20; A21 = B21; A22 = B22;
                Atx = CAp.x; Aty = CAp.y; Atz = CAp.z;
            } else {
                A00 = G00; A01 = G01; A02 = G02;
                A10 = G10; A11 = G11; A12 = G12;
                A20 = G20; A21 = G21; A22 = G22;
                Atx = Gx; Aty = Gy; Atz = Gz;
            }
            float n00 = A00 * f00 + A01 * f10 + A02 * f20;
            float n01 = A00 * f01 + A01 * f11 + A02 * f21;
            float n02 = A00 * f02 + A01 * f12 + A02 * f22;
            float n10 = A10 * f00 + A11 * f10 + A12 * f20;
            float n11 = A10 * f01 + A11 * f11 + A12 * f21;
            float n12 = A10 * f02 + A11 * f12 + A12 * f22;
            float n20 = A20 * f00 + A21 * f10 + A22 * f20;
            float n21 = A20 * f01 + A21 * f11 + A22 * f21;
            float n22 = A20 * f02 + A21 * f12 + A22 * f22;
            float ntx = A00 * d0.w + A01 * d1.w + A02 * d2.w + Atx;
            float nty = A10 * d0.w + A11 * d1.w + A12 * d2.w + Aty;
            float ntz = A20 * d0.w + A21 * d1.w + A22 * d2.w + Atz;
            G00 = n00; G01 = n01; G02 = n02;
            G10 = n10; G11 = n11; G12 = n12;
            G20 = n20; G21 = n21; G22 = n22;
            Gx = ntx; Gy = nty; Gz = ntz;

            // atoms whose group == g: read lit from LDS, place, store now
            #pragma unroll
            for (int a = 0; a < 10; a++) {
                bool sel = ((gpk >> (3 * a)) & 7u) == (unsigned)g;
                if (sel) {
                    bool mk = (mbit >> a) & 1u;
                    float lx = lrow[3*a], ly = lrow[3*a+1], lz = lrow[3*a+2];
                    float px = fmaf(G00, lx, fmaf(G01, ly, fmaf(G02, lz, Gx)));
                    float py = fmaf(G10, lx, fmaf(G11, ly, fmaf(G12, lz, Gy)));
                    float pz = fmaf(G20, lx, fmaf(G21, ly, fmaf(G22, lz, Gz)));
                    float* po = orow + 12 + 3 * a;
                    po[0] = mk ? px : 0.0f;
                    po[1] = mk ? py : 0.0f;
                    po[2] = mk ? pz : 0.0f;
                }
            }
        }
    }
}

extern "C" void kernel_launch(void* const* d_in, const int* in_sizes, int n_in,
                              void* d_out, int out_size, void* d_ws, size_t ws_size,
                              hipStream_t stream) {
    const int*   aa  = (const int*)d_in[0];
    const float* bb  = (const float*)d_in[1];
    const float* tor = (const float*)d_in[2];
    const float* df  = (const float*)d_in[3];
    const int*   gi  = (const int*)d_in[4];
    const float* am  = (const float*)d_in[5];
    const float* lp  = (const float*)d_in[6];
    float* outp = (float*)d_out;
    const int n = in_sizes[0];
    int tiles = (n + 255) / 256;
    int blocks = tiles < 1024 ? tiles : 1024;   // ~persistent grid-stride
    idealizer_kernel<<<blocks, 256, 0, stream>>>(aa, bb, tor, df, gi, am, lp, outp, n);
}

// Round 5
// 155.976 us; speedup vs baseline: 1.6086x; 1.1885x over previous
//
#include <hip/hip_runtime.h>

// Idealizer: torsion angles + backbone frames -> atom14 coordinates.
// One thread per residue; block processes a 256-residue tile. Tables in LDS.
// Group-scatter placement: walk groups 0..7 (kinematic chain); each atom's
// result is ds_written into a per-block LDS output tile at its (unique)
// matching group; tile is then copied to HBM with coalesced float2 stores.
//
// R1: 176 VGPR, reg-buffered row stores -> 93 us, WRITE clean 93 MB.
// R2: forced (256,4) -> 64 VGPR spill, WRITE 415 MB, 159 us.
// R4: lean 64-VGPR + scattered divergent dword stores -> WRITE 266 MB
//     (partial-line writeback amplification) + vmcnt store stalls, 95 us.
// R5: LDS output tile + barrier + coalesced copy-out: clean writes AND
//     no vmcnt stalls, keeps 64-VGPR compute.

struct F3 { float x, y, z; };

__device__ __forceinline__ F3 f3sub(F3 a, F3 b) { return {a.x-b.x, a.y-b.y, a.z-b.z}; }
__device__ __forceinline__ F3 f3cross(F3 a, F3 b) {
    return {a.y*b.z - a.z*b.y, a.z*b.x - a.x*b.z, a.x*b.y - a.y*b.x};
}
__device__ __forceinline__ float f3dot(F3 a, F3 b) { return a.x*b.x + a.y*b.y + a.z*b.z; }

// sin/cos of the dihedral angle directly (reference takes sincos(atan2(y,x))).
__device__ __forceinline__ void dihedral_sc(F3 p0, F3 p1, F3 p2, F3 p3,
                                            float& s, float& c) {
    F3 b0 = f3sub(p0, p1);          // -(p1 - p0)
    F3 b1 = f3sub(p2, p1);
    F3 b2 = f3sub(p3, p2);
    F3 u = f3cross(b0, b1);
    F3 v = f3cross(b2, b1);         // ref's "b1xb2" is cross(b2, b1)
    F3 w = f3cross(u, v);
    float y = f3dot(w, b1) * rsqrtf(fmaxf(f3dot(b1, b1), 1e-30f));
    float x = f3dot(u, v);
    float r2 = x*x + y*y;
    if (r2 > 1e-24f) {
        float rinv = rsqrtf(r2);
        s = y * rinv;
        c = x * rinv;
    } else {                        // atan2(0,0)=0 -> angle 0
        s = 0.0f;
        c = 1.0f;
    }
}

#define DF_STRIDE 132   // 128 + 4 pad dwords: spread per-aa rows across banks
#define LIT_STRIDE 36   // 30 used + 6 pad: 16B-aligned rows, bank spread

__global__ __launch_bounds__(256) void idealizer_kernel(
    const int*   __restrict__ aa,       // (n,)
    const float* __restrict__ bb,       // (n,4,3)
    const float* __restrict__ tor,      // (n,4)
    const float* __restrict__ dframes,  // (21,8,4,4)
    const int*   __restrict__ gidx,     // (21,14)
    const float* __restrict__ amask,    // (21,14)
    const float* __restrict__ lit,      // (21,14,3)
    float*       __restrict__ out,      // (n,14,3)
    int n)
{
    __shared__ __align__(16) float s_df[21 * DF_STRIDE];
    __shared__ __align__(16) float s_lit[21 * LIT_STRIDE];   // atoms 4..13 only
    __shared__ __align__(16) float s_out[256 * 42];          // output tile
    __shared__ unsigned s_gpk[21];   // 10 x 3-bit group ids (atoms 4..13)
    __shared__ unsigned s_mbit[21];  // 10 x 1-bit atom mask (atoms 4..13)

    const int tid = threadIdx.x;
    for (int j = tid; j < 21 * 128; j += 256)
        s_df[(j >> 7) * DF_STRIDE + (j & 127)] = dframes[j];
    for (int j = tid; j < 21 * 30; j += 256) {
        int a = j / 30, r = j - a * 30;
        s_lit[a * LIT_STRIDE + r] = lit[a * 42 + 12 + r];
    }
    if (tid < 21) {
        unsigned gp = 0, mb = 0;
        #pragma unroll
        for (int a = 0; a < 10; a++) {
            gp |= ((unsigned)gidx[tid * 14 + 4 + a]) << (3 * a);
            mb |= (amask[tid * 14 + 4 + a] != 0.0f ? 1u : 0u) << a;
        }
        s_gpk[tid] = gp;
        s_mbit[tid] = mb;
    }
    __syncthreads();

    for (int i0 = blockIdx.x * 256; i0 < n; i0 += gridDim.x * 256) {
        const int i = i0 + tid;
        if (i < n) {
            float* srow = &s_out[tid * 42];

            // ---- own residue backbone (12 floats) ----
            const float4* bb4 = (const float4*)bb;
            float4 q0 = bb4[i * 3 + 0];   // N.xyz, CA.x
            float4 q1 = bb4[i * 3 + 1];   // CA.yz, C.xy
            float4 q2 = bb4[i * 3 + 2];   // C.z, atom3.xyz
            F3 Np  = {q0.x, q0.y, q0.z};
            F3 CAp = {q0.w, q1.x, q1.y};
            F3 Cp  = {q1.z, q1.w, q2.x};

            // backbone passthrough -> LDS tile (atoms 0..3)
            float2* s2 = (float2*)srow;   // row base is 8B-aligned (168*tid)
            s2[0] = make_float2(q0.x, q0.y);
            s2[1] = make_float2(q0.z, q0.w);
            s2[2] = make_float2(q1.x, q1.y);
            s2[3] = make_float2(q1.z, q1.w);
            s2[4] = make_float2(q2.x, q2.y);
            s2[5] = make_float2(q2.z, q2.w);

            // ---- neighbors (clamped; boundary angles overridden below) ----
            const int im = (i > 0)     ? i - 1 : 0;
            const int ip = (i < n - 1) ? i + 1 : 0;
            F3 Cm = { bb[im * 12 + 6], bb[im * 12 + 7], bb[im * 12 + 8] };  // C[i-1]
            float4 r0 = bb4[ip * 3 + 0];                                     // N[i+1], CA[i+1].x
            float2 r1 = ((const float2*)bb)[ip * 6 + 2];                     // CA[i+1].yz
            F3 Nn  = {r0.x, r0.y, r0.z};
            F3 CAn = {r0.w, r1.x, r1.y};

            // ---- backbone dihedrals (sin/cos directly) ----
            float s_ph, c_ph, s_ps, c_ps, s_om, c_om;
            dihedral_sc(Cm,  Np,  CAp, Cp,  s_ph, c_ph);   // phi
            dihedral_sc(Np,  CAp, Cp,  Nn,  s_ps, c_ps);   // psi
            dihedral_sc(CAp, Cp,  Nn,  CAn, s_om, c_om);   // omega
            if (i == 0)     { s_ph = 0.0f; c_ph = 1.0f; }
            if (i == n - 1) { s_ps = 0.0f; c_ps = 1.0f; s_om = 0.0f; c_om = 1.0f; }

            // ---- backbone frame from reference (N, CA, C) ----
            const float eps = 1e-20f;
            F3 nv = f3sub(Np, CAp);
            F3 cv = f3sub(Cp, CAp);
            float cx = cv.x, cy = cv.y, cz = cv.z;
            float d2xy  = cx * cx + cy * cy;
            float inrm  = rsqrtf(eps + d2xy);
            float s1 = -cy * inrm, c1 = cx * inrm;
            float inrm2 = rsqrtf(eps + d2xy + cz * cz);
            float s2v = cz * inrm2, c2v = sqrtf(d2xy) * inrm2;
            float Rc00 = c2v * c1,  Rc01 = -c2v * s1, Rc02 = s2v;
            float Rc10 = s1,        Rc11 = c1,        Rc12 = 0.0f;
            float Rc20 = -s2v * c1, Rc21 = s2v * s1,  Rc22 = c2v;
            float n2y = Rc10 * nv.x + Rc11 * nv.y + Rc12 * nv.z;
            float n2z = Rc20 * nv.x + Rc21 * nv.y + Rc22 * nv.z;
            float inrm3 = rsqrtf(eps + n2y * n2y + n2z * n2z);
            float sn = -n2z * inrm3, cn = n2y * inrm3;
            float M10 = cn * Rc10 - sn * Rc20, M11 = cn * Rc11 - sn * Rc21, M12 = cn * Rc12 - sn * Rc22;
            float M20 = sn * Rc10 + cn * Rc20, M21 = sn * Rc11 + cn * Rc21, M22 = sn * Rc12 + cn * Rc22;
            // bb_r = (Rn @ Rc)^T
            float B00 = Rc00, B01 = M10, B02 = M20;
            float B10 = Rc01, B11 = M11, B12 = M21;
            float B20 = Rc02, B21 = M12, B22 = M22;

            // ---- per-frame sin/cos: [identity, omega, phi, psi, tor0..3] ----
            float4 tv = ((const float4*)tor)[i];
            float sang[8], cang[8];
            sang[0] = 0.0f; cang[0] = 1.0f;
            sang[1] = s_om; cang[1] = c_om;
            sang[2] = s_ph; cang[2] = c_ph;
            sang[3] = s_ps; cang[3] = c_ps;
            __sincosf(tv.x, &sang[4], &cang[4]);
            __sincosf(tv.y, &sang[5], &cang[5]);
            __sincosf(tv.z, &sang[6], &cang[6]);
            __sincosf(tv.w, &sang[7], &cang[7]);

            const int aai = aa[i];
            const unsigned gpk  = s_gpk[aai];
            const unsigned mbit = s_mbit[aai];
            const float* lrow = &s_lit[aai * LIT_STRIDE];

            // ---- group chain; ds_write each atom at its matching group ----
            float G00, G01, G02, G10, G11, G12, G20, G21, G22, Gx, Gy, Gz;
            const int dbase = aai * DF_STRIDE;
            #pragma unroll
            for (int g = 0; g < 8; g++) {
                const float4* dfr = (const float4*)&s_df[dbase + g * 16];
                float4 d0 = dfr[0], d1 = dfr[1], d2 = dfr[2];
                float sA = sang[g], cA = cang[g];
                // fr = dr @ Ra(angle)
                float f00 = d0.x, f01 = cA * d0.y + sA * d0.z, f02 = cA * d0.z - sA * d0.y;
                float f10 = d1.x, f11 = cA * d1.y + sA * d1.z, f12 = cA * d1.z - sA * d1.y;
                float f20 = d2.x, f21 = cA * d2.y + sA * d2.z, f22 = cA * d2.z - sA * d2.y;
                float A00, A01, A02, A10, A11, A12, A20, A21, A22, Atx, Aty, Atz;
                if (g <= 4) {
                    A00 = B00; A01 = B01; A02 = B02;
                    A10 = B10; A11 = B11; A12 = B12;
                    A20 = B20; A21 = B21; A22 = B22;
                    Atx = CAp.x; Aty = CAp.y; Atz = CAp.z;
                } else {
                    A00 = G00; A01 = G01; A02 = G02;
                    A10 = G10; A11 = G11; A12 = G12;
                    A20 = G20; A21 = G21; A22 = G22;
                    Atx = Gx; Aty = Gy; Atz = Gz;
                }
                float n00 = A00 * f00 + A01 * f10 + A02 * f20;
                float n01 = A00 * f01 + A01 * f11 + A02 * f21;
                float n02 = A00 * f02 + A01 * f12 + A02 * f22;
                float n10 = A10 * f00 + A11 * f10 + A12 * f20;
                float n11 = A10 * f01 + A11 * f11 + A12 * f21;
                float n12 = A10 * f02 + A11 * f12 + A12 * f22;
                float n20 = A20 * f00 + A21 * f10 + A22 * f20;
                float n21 = A20 * f01 + A21 * f11 + A22 * f21;
                float n22 = A20 * f02 + A21 * f12 + A22 * f22;
                float ntx = A00 * d0.w + A01 * d1.w + A02 * d2.w + Atx;
                float nty = A10 * d0.w + A11 * d1.w + A12 * d2.w + Aty;
                float ntz = A20 * d0.w + A21 * d1.w + A22 * d2.w + Atz;
                G00 = n00; G01 = n01; G02 = n02;
                G10 = n10; G11 = n11; G12 = n12;
                G20 = n20; G21 = n21; G22 = n22;
                Gx = ntx; Gy = nty; Gz = ntz;

                // atoms whose group == g: place, ds_write into the tile row
                #pragma unroll
                for (int a = 0; a < 10; a++) {
                    bool sel = ((gpk >> (3 * a)) & 7u) == (unsigned)g;
                    if (sel) {
                        float mk = ((mbit >> a) & 1u) ? 1.0f : 0.0f;
                        float lx = lrow[3*a], ly = lrow[3*a+1], lz = lrow[3*a+2];
                        float px = fmaf(G00, lx, fmaf(G01, ly, fmaf(G02, lz, Gx)));
                        float py = fmaf(G10, lx, fmaf(G11, ly, fmaf(G12, lz, Gy)));
                        float pz = fmaf(G20, lx, fmaf(G21, ly, fmaf(G22, lz, Gz)));
                        float* po = srow + 12 + 3 * a;
                        po[0] = mk * px;
                        po[1] = mk * py;
                        po[2] = mk * pz;
                    }
                }
            }
        }

        __syncthreads();

        // ---- coalesced tile copy-out: float2, consecutive lanes ----
        int m = n - i0; if (m > 256) m = 256;
        const int cnt2 = m * 21;                     // float2 count (42 floats/row)
        float2* gout = (float2*)(out + (size_t)i0 * 42);
        const float2* l2 = (const float2*)s_out;
        for (int off = tid; off < cnt2; off += 256)
            gout[off] = l2[off];

        __syncthreads();   // tile reusable next iteration
    }
}

extern "C" void kernel_launch(void* const* d_in, const int* in_sizes, int n_in,
                              void* d_out, int out_size, void* d_ws, size_t ws_size,
                              hipStream_t stream) {
    const int*   aa  = (const int*)d_in[0];
    const float* bb  = (const float*)d_in[1];
    const float* tor = (const float*)d_in[2];
    const float* df  = (const float*)d_in[3];
    const int*   gi  = (const int*)d_in[4];
    const float* am  = (const float*)d_in[5];
    const float* lp  = (const float*)d_in[6];
    float* outp = (float*)d_out;
    const int n = in_sizes[0];
    int tiles = (n + 255) / 256;
    int blocks = tiles < 1024 ? tiles : 1024;   // grid-stride
    idealizer_kernel<<<blocks, 256, 0, stream>>>(aa, bb, tor, df, gi, am, lp, outp, n);
}